// Round 1
// 121.959 us; speedup vs baseline: 1.0991x; 1.0991x over previous
//
#include <hip/hip_runtime.h>
#include <cstddef>

#define B_    4
#define CIN_  256
#define COUT_ 256
#define H_    64
#define W_    64
#define KK_   9
#define G_    4
#define PAD_  1
#define NSL   36          // 4 groups * 9 taps, K=64 each

typedef short bf16x8 __attribute__((ext_vector_type(8)));
typedef float f32x4  __attribute__((ext_vector_type(4)));
typedef __attribute__((address_space(1))) const unsigned int* gptr_t;
typedef __attribute__((address_space(3))) unsigned int*       lptr_t;

__device__ __forceinline__ unsigned short f2bf(float v) {
    unsigned int u = __float_as_uint(v);
    u += 0x7fffu + ((u >> 16) & 1u);
    return (unsigned short)(u >> 16);
}
__device__ __forceinline__ float f_lo(unsigned int u) { return __uint_as_float(u << 16); }
__device__ __forceinline__ float f_hi(unsigned int u) { return __uint_as_float(u & 0xffff0000u); }

// Merged prep: blocks [0,512): xT[b][h][w][c] bf16 NHWC transpose.
//              blocks [512,2816): wb weight repack (36 tiles, pos-swizzled).
__global__ __launch_bounds__(256) void prep_kernel(const float* __restrict__ x,
                                                   unsigned short* __restrict__ xT,
                                                   const float* __restrict__ w,
                                                   unsigned short* __restrict__ wb) {
    const int tid = threadIdx.x;
    if (blockIdx.x < 512) {
        __shared__ unsigned short s[128][66];
        const int bh    = blockIdx.x >> 1;
        const int chalf = blockIdx.x & 1;
        const size_t src_base = ((size_t)(bh >> 6) * CIN_ + chalf * 128) * (H_ * W_) + (bh & 63) * W_;
        #pragma unroll 4
        for (int k = 0; k < 32; ++k) {
            int i = k * 256 + tid;
            int c = i >> 6, ww = i & 63;
            s[c][ww] = f2bf(x[src_base + (size_t)c * (H_ * W_) + ww]);
        }
        __syncthreads();
        #pragma unroll 4
        for (int k = 0; k < 16; ++k) {
            int j  = k * 256 + tid;
            int c2 = (j & 63) * 2, ww = j >> 6;
            unsigned int lo = s[c2][ww], hi = s[c2 + 1][ww];
            *(unsigned int*)(xT + ((size_t)bh * 64 + ww) * 256 + chalf * 128 + c2) = lo | (hi << 16);
        }
    } else {
        int idx = (blockIdx.x - 512) * 256 + tid;   // 36*16384 exactly
        int e   = idx & 7;
        int pos = (idx >> 3) & 7;
        int o   = (idx >> 6) & 255;
        int t   = idx >> 14;                        // g*9 + kk
        int g   = t / 9, kk = t - g * 9;
        int j   = pos ^ (o & 7);
        int c   = g * 64 + j * 8 + e;
        wb[idx] = f2bf(w[(o * CIN_ + c) * KK_ + kk]);
    }
}

// Main kernel: 256 blocks x 512 threads. Block = (b, h): all 256 outs x 64 px,
// full K (36 steps). Double-buffered s_W/s_S, one barrier per step, fused relu.
__global__ __launch_bounds__(512, 2) void dcn_kernel(
    const unsigned short* __restrict__ xT, const float* __restrict__ y,
    const float* __restrict__ w_off, const unsigned short* __restrict__ wb,
    float* __restrict__ out)
{
    __shared__ unsigned short s_W[2][COUT_ * 64];   // 2 x 32 KB
    __shared__ unsigned short s_S[2][64 * 64];      // 2 x  8 KB

    const int tid = threadIdx.x;
    const int bid = blockIdx.x;                 // 256 blocks = 1/CU
    // XCD swizzle: each XCD (bid&7) owns one (b, h-half) slab -> ~2MB xT in its L2
    const int xcd = bid & 7;
    const int b   = xcd >> 1;
    const int h   = (xcd & 1) * 32 + (bid >> 3);

    // sampling mapping: 8 lanes per pixel (contiguous 128B gathers, L1-resident)
    const int sp = tid >> 3;      // pixel 0..63
    const int c8 = tid & 7;       // 8-channel chunk 0..7

    const float yv0 = y[((b * 2 + 0) * H_ + h) * W_ + sp];
    const float yv1 = y[((b * 2 + 1) * H_ + h) * W_ + sp];

    // mfma mapping: 8 waves, wave = 64 outs (oh) x 32 px (pg)
    const int lane = tid & 63, wave = tid >> 6;
    const int pg  = wave & 1, oh = wave >> 1;
    const int l15 = lane & 15, kq = lane >> 4, sw = l15 & 7;

    f32x4 acc[8];   // [nt][mt] : 2 px-subtiles x 4 out-subtiles
    #pragma unroll
    for (int i = 0; i < 8; ++i) acc[i] = (f32x4){0.f, 0.f, 0.f, 0.f};

    const size_t xbase = (size_t)b * (H_ * W_ * 256) + c8 * 8;

    // in-flight sample state for the next step
    float w00, w01, w10, w11;
    uint4 A, Bv, C, D;

#define ISSUE_SAMPLE(t) do {                                                   \
    const int g_ = (t) / 9, kk_ = (t) % 9;                                     \
    const float4 co = *(const float4*)(w_off + (t) * 4);                       \
    const float dy = fmaf(yv0, co.x, yv1 * co.y);                              \
    const float dx = fmaf(yv0, co.z, yv1 * co.w);                              \
    const float yc = (float)(h + (kk_ / 3) - PAD_) + dy;                       \
    const float xc = (float)(sp + (kk_ % 3) - PAD_) + dx;                      \
    const float yf = floorf(yc), xf = floorf(xc);                              \
    const float wy = yc - yf,    wx = xc - xf;                                 \
    const int   yi = (int)yf,    xi = (int)xf;                                 \
    float a00 = (1.f - wy) * (1.f - wx);                                       \
    float a01 = (1.f - wy) * wx;                                               \
    float a10 = wy * (1.f - wx);                                               \
    float a11 = wy * wx;                                                       \
    const bool y0ok = (yi >= 0) & (yi < H_);                                   \
    const bool y1ok = (yi >= -1) & (yi < H_ - 1);                              \
    const bool x0ok = (xi >= 0) & (xi < W_);                                   \
    const bool x1ok = (xi >= -1) & (xi < W_ - 1);                              \
    w00 = (y0ok & x0ok) ? a00 : 0.f;                                           \
    w01 = (y0ok & x1ok) ? a01 : 0.f;                                           \
    w10 = (y1ok & x0ok) ? a10 : 0.f;                                           \
    w11 = (y1ok & x1ok) ? a11 : 0.f;                                           \
    const int y0c = min(max(yi, 0), H_ - 1);                                   \
    const int y1c = min(max(yi + 1, 0), H_ - 1);                               \
    const int x0c = min(max(xi, 0), W_ - 1);                                   \
    const int x1c = min(max(xi + 1, 0), W_ - 1);                               \
    const unsigned short* xb = xT + xbase + g_ * 64;                           \
    A  = *(const uint4*)(xb + ((size_t)y0c * W_ + x0c) * 256);                 \
    Bv = *(const uint4*)(xb + ((size_t)y0c * W_ + x1c) * 256);                 \
    C  = *(const uint4*)(xb + ((size_t)y1c * W_ + x0c) * 256);                 \
    D  = *(const uint4*)(xb + ((size_t)y1c * W_ + x1c) * 256);                 \
} while (0)

#define STAGE_W(t, buf) do {                                                   \
    const unsigned short* src = wb + (size_t)(t) * 16384;                      \
    _Pragma("unroll")                                                          \
    for (int j = 0; j < 4; ++j) {                                              \
        const int off = (j * 512 + tid) * 8;                                   \
        __builtin_amdgcn_global_load_lds((gptr_t)(src + off),                  \
                                         (lptr_t)(s_W[buf] + off), 16, 0, 0);  \
    }                                                                          \
} while (0)

#define WRITE_SAMPLE(buf) do {                                                 \
    const unsigned int av[4] = {A.x, A.y, A.z, A.w};                           \
    const unsigned int bv[4] = {Bv.x, Bv.y, Bv.z, Bv.w};                       \
    const unsigned int cv[4] = {C.x, C.y, C.z, C.w};                           \
    const unsigned int dv[4] = {D.x, D.y, D.z, D.w};                           \
    unsigned int res[4];                                                       \
    _Pragma("unroll")                                                          \
    for (int q = 0; q < 4; ++q) {                                              \
        float rl = w00 * f_lo(av[q]);                                          \
        rl = fmaf(w01, f_lo(bv[q]), rl);                                       \
        rl = fmaf(w10, f_lo(cv[q]), rl);                                       \
        rl = fmaf(w11, f_lo(dv[q]), rl);                                       \
        float rh = w00 * f_hi(av[q]);                                          \
        rh = fmaf(w01, f_hi(bv[q]), rh);                                       \
        rh = fmaf(w10, f_hi(cv[q]), rh);                                       \
        rh = fmaf(w11, f_hi(dv[q]), rh);                                       \
        res[q] = __builtin_amdgcn_perm(__float_as_uint(rh),                    \
                                       __float_as_uint(rl), 0x07060302u);      \
    }                                                                          \
    *(uint4*)(s_S[buf] + sp * 64 + ((c8 ^ (sp & 7)) * 8)) =                    \
        make_uint4(res[0], res[1], res[2], res[3]);                            \
} while (0)

#define MFMA_STEP(buf) do {                                                    \
    bf16x8 bf[2][2], af[2][4];                                                 \
    _Pragma("unroll")                                                          \
    for (int kh = 0; kh < 2; ++kh) {                                           \
        const int pos = ((kh * 4 + kq) ^ sw) * 8;                              \
        _Pragma("unroll")                                                      \
        for (int nt = 0; nt < 2; ++nt)                                         \
            bf[kh][nt] = *(const bf16x8*)(s_S[buf] +                           \
                              (pg * 32 + nt * 16 + l15) * 64 + pos);           \
        _Pragma("unroll")                                                      \
        for (int mt = 0; mt < 4; ++mt)                                         \
            af[kh][mt] = *(const bf16x8*)(s_W[buf] +                           \
                              (oh * 64 + mt * 16 + l15) * 64 + pos);           \
    }                                                                          \
    __builtin_amdgcn_s_setprio(1);                                             \
    _Pragma("unroll")                                                          \
    for (int kh = 0; kh < 2; ++kh)                                             \
        _Pragma("unroll")                                                      \
        for (int nt = 0; nt < 2; ++nt)                                         \
            _Pragma("unroll")                                                  \
            for (int mt = 0; mt < 4; ++mt)                                     \
                acc[nt * 4 + mt] = __builtin_amdgcn_mfma_f32_16x16x32_bf16(    \
                    af[kh][mt], bf[kh][nt], acc[nt * 4 + mt], 0, 0, 0);        \
    __builtin_amdgcn_s_setprio(0);                                             \
} while (0)

    // ---- prologue: stage step 0 into buffer 0 ----
    ISSUE_SAMPLE(0);
    STAGE_W(0, 0);
    WRITE_SAMPLE(0);
    __syncthreads();

    // ---- main loop: one barrier per step; prefetch s+1 under MFMA of s ----
    for (int s = 0; s < NSL; s += 2) {
        // even step: compute buf 0, prefetch into buf 1
        ISSUE_SAMPLE(s + 1);               // s+1 <= 35 always
        STAGE_W(s + 1, 1);
        __builtin_amdgcn_sched_barrier(0); // pin load issue before compute
        MFMA_STEP(0);
        WRITE_SAMPLE(1);
        __syncthreads();                   // drains DMA(s+1) + ds_writes

        // odd step: compute buf 1, prefetch into buf 0
        if (s + 2 < NSL) {
            ISSUE_SAMPLE(s + 2);
            STAGE_W(s + 2, 0);
        }
        __builtin_amdgcn_sched_barrier(0);
        MFMA_STEP(1);
        if (s + 2 < NSL) WRITE_SAMPLE(0);
        __syncthreads();
    }

    // ---- epilogue: fused relu, direct final store. C/D: col->px, row->o ----
    #pragma unroll
    for (int nt = 0; nt < 2; ++nt) {
        const int px = pg * 32 + nt * 16 + l15;
        #pragma unroll
        for (int mt = 0; mt < 4; ++mt) {
            const int obase = oh * 64 + mt * 16 + kq * 4;
            #pragma unroll
            for (int r = 0; r < 4; ++r) {
                out[(((size_t)b * COUT_ + obase + r) * H_ + h) * W_ + px] =
                    fmaxf(acc[nt * 4 + mt][r], 0.f);
            }
        }
    }
#undef ISSUE_SAMPLE
#undef STAGE_W
#undef WRITE_SAMPLE
#undef MFMA_STEP
}

extern "C" void kernel_launch(void* const* d_in, const int* in_sizes, int n_in,
                              void* d_out, int out_size, void* d_ws, size_t ws_size,
                              hipStream_t stream) {
    const float* x     = (const float*)d_in[0];
    const float* y     = (const float*)d_in[1];
    const float* w_off = (const float*)d_in[2];
    const float* w_def = (const float*)d_in[3];
    float* out = (float*)d_out;

    unsigned short* xT = (unsigned short*)d_ws;             // 8 MB
    unsigned short* wb = (unsigned short*)d_ws + 4194304;   // 1.18 MB

    prep_kernel<<<2816, 256, 0, stream>>>(x, xT, w_def, wb);
    dcn_kernel<<<256, 512, 0, stream>>>(xT, y, w_off, wb, out);
}

// Round 2
// 121.495 us; speedup vs baseline: 1.1033x; 1.0038x over previous
//
#include <hip/hip_runtime.h>
#include <cstddef>

#define B_    4
#define CIN_  256
#define COUT_ 256
#define H_    64
#define W_    64
#define KK_   9
#define G_    4
#define PAD_  1
#define NSL   36          // 4 groups * 9 taps, K=64 each

typedef short bf16x8 __attribute__((ext_vector_type(8)));
typedef float f32x4  __attribute__((ext_vector_type(4)));
typedef __attribute__((address_space(1))) const unsigned int* gptr_t;
typedef __attribute__((address_space(3))) unsigned int*       lptr_t;

__device__ __forceinline__ unsigned short f2bf(float v) {
    unsigned int u = __float_as_uint(v);
    u += 0x7fffu + ((u >> 16) & 1u);
    return (unsigned short)(u >> 16);
}
__device__ __forceinline__ float f_lo(unsigned int u) { return __uint_as_float(u << 16); }
__device__ __forceinline__ float f_hi(unsigned int u) { return __uint_as_float(u & 0xffff0000u); }

// Merged prep: blocks [0,512): xT[b][h][w][c] bf16 NHWC transpose.
//              blocks [512,2816): wb weight repack (36 tiles, pos-swizzled).
__global__ __launch_bounds__(256) void prep_kernel(const float* __restrict__ x,
                                                   unsigned short* __restrict__ xT,
                                                   const float* __restrict__ w,
                                                   unsigned short* __restrict__ wb) {
    const int tid = threadIdx.x;
    if (blockIdx.x < 512) {
        __shared__ unsigned short s[128][66];
        const int bh    = blockIdx.x >> 1;
        const int chalf = blockIdx.x & 1;
        const size_t src_base = ((size_t)(bh >> 6) * CIN_ + chalf * 128) * (H_ * W_) + (bh & 63) * W_;
        #pragma unroll 4
        for (int k = 0; k < 32; ++k) {
            int i = k * 256 + tid;
            int c = i >> 6, ww = i & 63;
            s[c][ww] = f2bf(x[src_base + (size_t)c * (H_ * W_) + ww]);
        }
        __syncthreads();
        #pragma unroll 4
        for (int k = 0; k < 16; ++k) {
            int j  = k * 256 + tid;
            int c2 = (j & 63) * 2, ww = j >> 6;
            unsigned int lo = s[c2][ww], hi = s[c2 + 1][ww];
            *(unsigned int*)(xT + ((size_t)bh * 64 + ww) * 256 + chalf * 128 + c2) = lo | (hi << 16);
        }
    } else {
        int idx = (blockIdx.x - 512) * 256 + tid;   // 36*16384 exactly
        int e   = idx & 7;
        int pos = (idx >> 3) & 7;
        int o   = (idx >> 6) & 255;
        int t   = idx >> 14;                        // g*9 + kk
        int g   = t / 9, kk = t - g * 9;
        int j   = pos ^ (o & 7);
        int c   = g * 64 + j * 8 + e;
        wb[idx] = f2bf(w[(o * CIN_ + c) * KK_ + kk]);
    }
}

// Main kernel: 256 blocks x 512 threads. Block = (b, h): 256 outs x 64 px,
// full K (36 steps). 3-buffer W pipeline with raw barriers + counted vmcnt:
// DMA(s+2) issued in step s, waited (via the sample-gather vmcnt(4)) at end of
// step s+1 -- it stays in flight across one barrier, never drained to 0.
__global__ __launch_bounds__(512, 2) void dcn_kernel(
    const unsigned short* __restrict__ xT, const float* __restrict__ y,
    const float* __restrict__ w_off, const unsigned short* __restrict__ wb,
    float* __restrict__ out)
{
    __shared__ unsigned short s_W[3][COUT_ * 64];   // 3 x 32 KB
    __shared__ unsigned short s_S[2][64 * 64];      // 2 x  8 KB

    const int tid = threadIdx.x;
    const int bid = blockIdx.x;                 // 256 blocks = 1/CU
    // XCD swizzle: each XCD (bid&7) owns one (b, h-half) slab -> ~2MB xT in its L2
    const int xcd = bid & 7;
    const int b   = xcd >> 1;
    const int h   = (xcd & 1) * 32 + (bid >> 3);

    // sampling mapping: 8 lanes per pixel (contiguous 128B gathers)
    const int sp = tid >> 3;      // pixel 0..63
    const int c8 = tid & 7;       // 8-channel chunk 0..7

    const float yv0 = y[((b * 2 + 0) * H_ + h) * W_ + sp];
    const float yv1 = y[((b * 2 + 1) * H_ + h) * W_ + sp];

    // mfma mapping: 8 waves, wave = 64 outs (oh) x 32 px (pg)
    const int lane = tid & 63, wave = tid >> 6;
    const int pg  = wave & 1, oh = wave >> 1;
    const int l15 = lane & 15, kq = lane >> 4, sw = l15 & 7;

    f32x4 acc[8];   // [nt][mt] : 2 px-subtiles x 4 out-subtiles
    #pragma unroll
    for (int i = 0; i < 8; ++i) acc[i] = (f32x4){0.f, 0.f, 0.f, 0.f};

    const size_t xbase = (size_t)b * (H_ * W_ * 256) + c8 * 8;

    // in-flight sample state for the next step
    float w00, w01, w10, w11;
    uint4 A, Bv, C, D;

#define ISSUE_SAMPLE(t) do {                                                   \
    const int g_ = (t) / 9, kk_ = (t) % 9;                                     \
    const float4 co = *(const float4*)(w_off + (t) * 4);                       \
    const float dy = fmaf(yv0, co.x, yv1 * co.y);                              \
    const float dx = fmaf(yv0, co.z, yv1 * co.w);                              \
    const float yc = (float)(h + (kk_ / 3) - PAD_) + dy;                       \
    const float xc = (float)(sp + (kk_ % 3) - PAD_) + dx;                      \
    const float yf = floorf(yc), xf = floorf(xc);                              \
    const float wy = yc - yf,    wx = xc - xf;                                 \
    const int   yi = (int)yf,    xi = (int)xf;                                 \
    float a00 = (1.f - wy) * (1.f - wx);                                       \
    float a01 = (1.f - wy) * wx;                                               \
    float a10 = wy * (1.f - wx);                                               \
    float a11 = wy * wx;                                                       \
    const bool y0ok = (yi >= 0) & (yi < H_);                                   \
    const bool y1ok = (yi >= -1) & (yi < H_ - 1);                              \
    const bool x0ok = (xi >= 0) & (xi < W_);                                   \
    const bool x1ok = (xi >= -1) & (xi < W_ - 1);                              \
    w00 = (y0ok & x0ok) ? a00 : 0.f;                                           \
    w01 = (y0ok & x1ok) ? a01 : 0.f;                                           \
    w10 = (y1ok & x0ok) ? a10 : 0.f;                                           \
    w11 = (y1ok & x1ok) ? a11 : 0.f;                                           \
    const int y0c = min(max(yi, 0), H_ - 1);                                   \
    const int y1c = min(max(yi + 1, 0), H_ - 1);                               \
    const int x0c = min(max(xi, 0), W_ - 1);                                   \
    const int x1c = min(max(xi + 1, 0), W_ - 1);                               \
    const unsigned short* xb = xT + xbase + g_ * 64;                           \
    A  = *(const uint4*)(xb + ((size_t)y0c * W_ + x0c) * 256);                 \
    Bv = *(const uint4*)(xb + ((size_t)y0c * W_ + x1c) * 256);                 \
    C  = *(const uint4*)(xb + ((size_t)y1c * W_ + x0c) * 256);                 \
    D  = *(const uint4*)(xb + ((size_t)y1c * W_ + x1c) * 256);                 \
} while (0)

#define STAGE_W(t, buf) do {                                                   \
    const unsigned short* src = wb + (size_t)(t) * 16384;                      \
    _Pragma("unroll")                                                          \
    for (int j = 0; j < 4; ++j) {                                              \
        const int off = (j * 512 + tid) * 8;                                   \
        __builtin_amdgcn_global_load_lds((gptr_t)(src + off),                  \
                                         (lptr_t)(s_W[buf] + off), 16, 0, 0); \
    }                                                                          \
} while (0)

#define WRITE_SAMPLE(buf) do {                                                 \
    const unsigned int av[4] = {A.x, A.y, A.z, A.w};                           \
    const unsigned int bv[4] = {Bv.x, Bv.y, Bv.z, Bv.w};                       \
    const unsigned int cv[4] = {C.x, C.y, C.z, C.w};                           \
    const unsigned int dv[4] = {D.x, D.y, D.z, D.w};                           \
    unsigned int res[4];                                                       \
    _Pragma("unroll")                                                          \
    for (int q = 0; q < 4; ++q) {                                              \
        float rl = w00 * f_lo(av[q]);                                          \
        rl = fmaf(w01, f_lo(bv[q]), rl);                                       \
        rl = fmaf(w10, f_lo(cv[q]), rl);                                       \
        rl = fmaf(w11, f_lo(dv[q]), rl);                                       \
        float rh = w00 * f_hi(av[q]);                                          \
        rh = fmaf(w01, f_hi(bv[q]), rh);                                       \
        rh = fmaf(w10, f_hi(cv[q]), rh);                                       \
        rh = fmaf(w11, f_hi(dv[q]), rh);                                       \
        res[q] = __builtin_amdgcn_perm(__float_as_uint(rh),                    \
                                       __float_as_uint(rl), 0x07060302u);      \
    }                                                                          \
    *(uint4*)(s_S[buf] + sp * 64 + ((c8 ^ (sp & 7)) * 8)) =                    \
        make_uint4(res[0], res[1], res[2], res[3]);                            \
} while (0)

#define MFMA_STEP(wb_, sb_) do {                                               \
    bf16x8 bf[2][2], af[2][4];                                                 \
    _Pragma("unroll")                                                          \
    for (int kh = 0; kh < 2; ++kh) {                                           \
        const int pos = ((kh * 4 + kq) ^ sw) * 8;                              \
        _Pragma("unroll")                                                      \
        for (int nt = 0; nt < 2; ++nt)                                         \
            bf[kh][nt] = *(const bf16x8*)(s_S[sb_] +                           \
                              (pg * 32 + nt * 16 + l15) * 64 + pos);           \
        _Pragma("unroll")                                                      \
        for (int mt = 0; mt < 4; ++mt)                                         \
            af[kh][mt] = *(const bf16x8*)(s_W[wb_] +                           \
                              (oh * 64 + mt * 16 + l15) * 64 + pos);           \
    }                                                                          \
    __builtin_amdgcn_s_setprio(1);                                             \
    _Pragma("unroll")                                                          \
    for (int kh = 0; kh < 2; ++kh)                                             \
        _Pragma("unroll")                                                      \
        for (int nt = 0; nt < 2; ++nt)                                         \
            _Pragma("unroll")                                                  \
            for (int mt = 0; mt < 4; ++mt)                                     \
                acc[nt * 4 + mt] = __builtin_amdgcn_mfma_f32_16x16x32_bf16(    \
                    af[kh][mt], bf[kh][nt], acc[nt * 4 + mt], 0, 0, 0);        \
    __builtin_amdgcn_s_setprio(0);                                             \
} while (0)

// One step. WCUR = s%3 (MFMA source), WPRE = (s+2)%3 (DMA dest),
// SCUR = s%2 (MFMA B-source), SNXT = (s+1)%2 (sample dest).
// Invariant entering step s: DMA(s+1) is the only outstanding vmem (4 instrs).
// WRITE_SAMPLE's compiler-wait on the gathers (vmcnt(4): 4 DMA issued after
// them) retires DMA(s+1); DMA(s+2) crosses the barrier in flight.
#define STEP(s_, WCUR, WPRE, SCUR, SNXT, DO_ISS, DO_STG, DO_BAR) do {          \
    if (DO_ISS) ISSUE_SAMPLE((s_) + 1);                                        \
    __builtin_amdgcn_sched_barrier(0);                                         \
    if (DO_STG) STAGE_W((s_) + 2, WPRE);                                       \
    __builtin_amdgcn_sched_barrier(0);                                         \
    MFMA_STEP(WCUR, SCUR);                                                     \
    __builtin_amdgcn_sched_barrier(0);                                         \
    if (DO_ISS) WRITE_SAMPLE(SNXT);                                            \
    __builtin_amdgcn_sched_barrier(0);                                         \
    if (DO_BAR) {                                                              \
        asm volatile("s_waitcnt lgkmcnt(0)" ::: "memory");                     \
        __builtin_amdgcn_sched_barrier(0);                                     \
        __builtin_amdgcn_s_barrier();                                          \
        __builtin_amdgcn_sched_barrier(0);                                     \
    }                                                                          \
} while (0)

    // ---- prologue: stage steps 0,1; leave DMA(1) in flight at the barrier ----
    ISSUE_SAMPLE(0);
    __builtin_amdgcn_sched_barrier(0);
    STAGE_W(0, 0);
    __builtin_amdgcn_sched_barrier(0);
    WRITE_SAMPLE(0);                 // waits gathers(0); may drain DMA(0) too
    __builtin_amdgcn_sched_barrier(0);
    STAGE_W(1, 1);
    __builtin_amdgcn_sched_barrier(0);
    asm volatile("s_waitcnt vmcnt(4) lgkmcnt(0)" ::: "memory");  // DMA(0) done
    __builtin_amdgcn_sched_barrier(0);
    __builtin_amdgcn_s_barrier();
    __builtin_amdgcn_sched_barrier(0);

    // ---- main loop: 5 x 6 steps (buffer indices static), then 6-step tail ----
    for (int sb = 0; sb < 30; sb += 6) {
        STEP(sb + 0, 0, 2, 0, 1, 1, 1, 1);
        STEP(sb + 1, 1, 0, 1, 0, 1, 1, 1);
        STEP(sb + 2, 2, 1, 0, 1, 1, 1, 1);
        STEP(sb + 3, 0, 2, 1, 0, 1, 1, 1);
        STEP(sb + 4, 1, 0, 0, 1, 1, 1, 1);
        STEP(sb + 5, 2, 1, 1, 0, 1, 1, 1);
    }
    STEP(30, 0, 2, 0, 1, 1, 1, 1);
    STEP(31, 1, 0, 1, 0, 1, 1, 1);
    STEP(32, 2, 1, 0, 1, 1, 1, 1);
    STEP(33, 0, 2, 1, 0, 1, 1, 1);
    STEP(34, 1, 0, 0, 1, 1, 0, 1);   // no STAGE(36): WRITE(35) waits vmcnt(0)
    STEP(35, 2, 1, 1, 0, 0, 0, 0);   // last MFMA; no barrier before epilogue

    // ---- epilogue: fused relu, direct final store. C/D: col->px, row->o ----
    #pragma unroll
    for (int nt = 0; nt < 2; ++nt) {
        const int px = pg * 32 + nt * 16 + l15;
        #pragma unroll
        for (int mt = 0; mt < 4; ++mt) {
            const int obase = oh * 64 + mt * 16 + kq * 4;
            #pragma unroll
            for (int r = 0; r < 4; ++r) {
                out[(((size_t)b * COUT_ + obase + r) * H_ + h) * W_ + px] =
                    fmaxf(acc[nt * 4 + mt][r], 0.f);
            }
        }
    }
#undef ISSUE_SAMPLE
#undef STAGE_W
#undef WRITE_SAMPLE
#undef MFMA_STEP
#undef STEP
}

extern "C" void kernel_launch(void* const* d_in, const int* in_sizes, int n_in,
                              void* d_out, int out_size, void* d_ws, size_t ws_size,
                              hipStream_t stream) {
    const float* x     = (const float*)d_in[0];
    const float* y     = (const float*)d_in[1];
    const float* w_off = (const float*)d_in[2];
    const float* w_def = (const float*)d_in[3];
    float* out = (float*)d_out;

    unsigned short* xT = (unsigned short*)d_ws;             // 8 MB
    unsigned short* wb = (unsigned short*)d_ws + 4194304;   // 1.18 MB

    prep_kernel<<<2816, 256, 0, stream>>>(x, xT, w_def, wb);
    dcn_kernel<<<256, 512, 0, stream>>>(xT, y, w_off, wb, out);
}